// Round 6
// baseline (1070.713 us; speedup 1.0000x reference)
//
#include <hip/hip_runtime.h>
#include <hip/hip_bf16.h>

// ---------------------------------------------------------------------------
// WeightOnlyLinear: y = x @ dequant4(qweight, scales, qzeros) + bias
//   x (8192,4096) fp32 | scales (32,12288) | bias (12288) | qweight (512,12288)
//   qzeros (32,1536) | out (8192,12288) fp32
// R6: FUSED int4-B GEMM on the R4 ring skeleton. B stays packed int4 in LDS
//     (4B/frag instead of 16B); dequant to bf16 at fragment-read time (VALU
//     pipe, overlaps MFMA). LDS traffic/phase 128KB -> 92KB. Kills the
//     dequant prepass. Ring-of-4 slots (A 16KB + Bq 4KB = 20KB each).
// ---------------------------------------------------------------------------

typedef __attribute__((ext_vector_type(8))) short short8;
typedef __attribute__((ext_vector_type(4))) float f32x4;

__device__ __forceinline__ short f2bf(float f) {
  unsigned u = __float_as_uint(f);
  u += 0x7fffu + ((u >> 16) & 1u);
  return (short)(u >> 16);
}

__device__ __forceinline__ void gload_lds16(const void* g, void* l) {
  __builtin_amdgcn_global_load_lds(
      (const __attribute__((address_space(1))) void*)g,
      (__attribute__((address_space(3))) void*)l,
      16, 0, 0);
}
__device__ __forceinline__ void gload_lds4(const void* g, void* l) {
  __builtin_amdgcn_global_load_lds(
      (const __attribute__((address_space(1))) void*)g,
      (__attribute__((address_space(3))) void*)l,
      4, 0, 0);
}

__device__ __forceinline__ void bar() {
  asm volatile("" ::: "memory");
  __builtin_amdgcn_s_barrier();
  asm volatile("" ::: "memory");
}
__device__ __forceinline__ void wait_vm8() {
  asm volatile("s_waitcnt vmcnt(8)" ::: "memory");
}
__device__ __forceinline__ void wait_vm4() {
  asm volatile("s_waitcnt vmcnt(4)" ::: "memory");
}
__device__ __forceinline__ void wait_vm0() {
  asm volatile("s_waitcnt vmcnt(0)" ::: "memory");
}

// dequant one packed word -> 8 bf16 (RNE, matches prepass bit-exactly)
__device__ __forceinline__ short8 dq8(int w, float sc, float zsc) {
  const unsigned we = (unsigned)w & 0x0f0f0f0fu;         // nibbles 0,2,4,6
  const unsigned wo = ((unsigned)w >> 4) & 0x0f0f0f0fu;  // nibbles 1,3,5,7
  short8 r;
  r[0] = f2bf(fmaf((float)(we & 0xffu), sc, zsc));
  r[1] = f2bf(fmaf((float)(wo & 0xffu), sc, zsc));
  r[2] = f2bf(fmaf((float)((we >> 8) & 0xffu), sc, zsc));
  r[3] = f2bf(fmaf((float)((wo >> 8) & 0xffu), sc, zsc));
  r[4] = f2bf(fmaf((float)((we >> 16) & 0xffu), sc, zsc));
  r[5] = f2bf(fmaf((float)((wo >> 16) & 0xffu), sc, zsc));
  r[6] = f2bf(fmaf((float)(we >> 24), sc, zsc));
  r[7] = f2bf(fmaf((float)(wo >> 24), sc, zsc));
  return r;
}

// ---------------------------------------------------------------------------
// Pass 1 (fallback only): dequant + transpose. qweight -> Wt (N,K) bf16.
// ---------------------------------------------------------------------------
__global__ __launch_bounds__(256) void dequant_kernel(
    const int* __restrict__ qweight, const int* __restrict__ qzeros,
    const float* __restrict__ scales, short* __restrict__ Wt,
    int in_f, int out_f) {
  __shared__ __align__(16) short T[64][72];
  const int n0 = blockIdx.x * 64;
  const int k0 = blockIdx.y * 64;
  const int t = threadIdx.x;
  const int nl = t & 63;
  const int kw = t >> 6;
  const int n = n0 + nl;
  const int g = k0 >> 7;
  const float sc = scales[(size_t)g * out_f + n];
  const int zpw = qzeros[(size_t)g * (out_f >> 3) + (n >> 3)];
  const float zp = (float)(((zpw >> ((n & 7) * 4)) & 15) + 1);
  const float zs = zp * sc;
#pragma unroll
  for (int rr = 0; rr < 2; ++rr) {
    const int kwi = kw + rr * 4;
    const int w = qweight[(size_t)((k0 >> 3) + kwi) * out_f + n];
    short8 v;
#pragma unroll
    for (int e = 0; e < 8; ++e) {
      float f = (float)((w >> (4 * e)) & 15) * sc - zs;
      v[e] = f2bf(f);
    }
    *(short8*)&T[nl][kwi * 8] = v;
  }
  __syncthreads();
#pragma unroll
  for (int rr = 0; rr < 2; ++rr) {
    const int c = rr * 256 + t;
    const int row = c >> 3, ch = c & 7;
    *(short8*)&Wt[(size_t)(n0 + row) * in_f + k0 + ch * 8] =
        *(const short8*)&T[row][ch * 8];
  }
}

// ---------------------------------------------------------------------------
// Pass 2: x fp32 -> bf16.
// ---------------------------------------------------------------------------
__global__ __launch_bounds__(256) void cvt_kernel(
    const float* __restrict__ x, short* __restrict__ xb, long n8) {
  long i = (long)blockIdx.x * blockDim.x + threadIdx.x;
  if (i >= n8) return;
  const float* src = x + i * 8;
  float4 a = *(const float4*)src;
  float4 b = *(const float4*)(src + 4);
  short8 v;
  v[0] = f2bf(a.x); v[1] = f2bf(a.y); v[2] = f2bf(a.z); v[3] = f2bf(a.w);
  v[4] = f2bf(b.x); v[5] = f2bf(b.y); v[6] = f2bf(b.z); v[7] = f2bf(b.w);
  *(short8*)(xb + i * 8) = v;
}

// ---------------------------------------------------------------------------
// Pass 3 (R6): fused 256x256 GEMM, 512 thr = 8 waves (2M x 4N), wave 128x64.
// LDS (80KB): A ring 4 x 16KB at slot*16384 (XOR-swizzled bf16, as R4);
//             Bq ring 4 x 4KB at 65536 + slot*4096 (packed int4 words,
//             word (n,kw) at dword n*4+kw; staged with swizzled global src
//             so dest = wavebase + lane*4; read = ds_read_b32, <=2-way).
// Body q: {wait vmcnt; bar} -> 4x b32 (B words) + 4x b128 (A mh0) ->
//         stage slot q+3 (2x16B A + 2x4B B) -> dequant 4 words (VALU) ->
//         16 MFMA mh0 -> 4x b128 (A mh1) -> 16 MFMA mh1.
// Scales/zeros per group g = q/4: 8 VMEM loads issued at qq3, consumed after
// qq0's vmcnt(4). Ledger: qq0: vm4; qq1/2/3: vm8. Last group peeled:
// vm4 / vm8 / vm4 / vm0.
// ---------------------------------------------------------------------------
#define GBM 256
#define GBN 256

__global__ __launch_bounds__(512, 2) void gemm_fused_kernel(
    const short* __restrict__ A, const int* __restrict__ qweight,
    const int* __restrict__ qzeros, const float* __restrict__ scales,
    const float* __restrict__ bias, float* __restrict__ C,
    int M, int N, int K) {
  __shared__ __align__(16) char lds[81920];
  const int tid = threadIdx.x;
  const int nbx = N / GBN;
  const int nwg = gridDim.x;
  int bid = blockIdx.x;
  if ((nwg & 7) == 0) bid = (bid & 7) * (nwg >> 3) + (bid >> 3);  // T1
  const int bm = (bid / nbx) * GBM;
  const int bn = (bid % nbx) * GBN;

  const int wid = tid >> 6, lane = tid & 63;
  const int wr = wid >> 2, wc = wid & 3;  // 2x4 wave grid
  const int lrow = lane & 15;
  const int lq = lane >> 4;

  const int P = K >> 5;  // K-halves; P = 4*G, P >= 4
  const int G = K >> 7;  // groups (GROUPSIZE=128)

  // A ds_read base (XOR swizzle, R4-verbatim)
  const int rowA = wr * 128 + lrow;
  const int sA = lq ^ ((rowA >> 1) & 3);
  const int baseA = rowA * 64 + sA * 16;

  // B word-read byte offsets per j (within lds; word idx = n*4 + lq)
  int offBq[4];
#pragma unroll
  for (int j = 0; j < 4; ++j) {
    const int n = wc * 64 + j * 16 + lrow;
    offBq[j] = 65536 + (n * 4 + lq) * 4;
  }

  // A staging: chunks c0=tid, c1=tid+512 (inverse-swizzled source)
  const int c0 = tid, c1 = tid + 512;
  const int rA0 = c0 >> 2, qA0 = (c0 & 3) ^ ((rA0 >> 1) & 3);
  const int rA1 = c1 >> 2, qA1 = (c1 & 3) ^ ((rA1 >> 1) & 3);
  const short* srcA0 = A + (size_t)(bm + rA0) * K + qA0 * 8;
  const short* srcA1 = A + (size_t)(bm + rA1) * K + qA1 * 8;
  const int dA0 = c0 * 16, dA1 = c1 * 16;

  // B staging: dest dwords w_d = tid, tid+512; n = w_d>>2, kw = w_d&3;
  // global word = (q*4+kw)*N + bn + n  (per-lane swizzled source)
  const int nB0 = c0 >> 2, kwB0 = c0 & 3;
  const int nB1 = c1 >> 2, kwB1 = c1 & 3;
  const int* srcB0 = qweight + (size_t)kwB0 * N + bn + nB0;
  const int* srcB1 = qweight + (size_t)kwB1 * N + bn + nB1;
  const int dB0 = 65536 + c0 * 4, dB1 = 65536 + c1 * 4;

  auto STAGE = [&](int slot, int q) {
    char* sa = &lds[slot * 16384];
    gload_lds16(srcA0 + q * 32, sa + dA0);
    gload_lds16(srcA1 + q * 32, sa + dA1);
    char* sq = &lds[slot * 4096];
    gload_lds4(srcB0 + (size_t)q * 4 * N, sq + dB0);
    gload_lds4(srcB1 + (size_t)q * 4 * N, sq + dB1);
  };

  // scales/zeros: next-group staging regs + current dequant constants
  float scN[4], scC[4], zscC[4];
  int zwN[4];
  const int shz = (lrow & 7) * 4;  // nibble shift (n&7 == lrow&7 here)
  auto LOADSZ = [&](int g) {
#pragma unroll
    for (int j = 0; j < 4; ++j) {
      scN[j] = scales[(size_t)g * N + bn + wc * 64 + j * 16 + lrow];
      zwN[j] = qzeros[(size_t)g * (N >> 3) + (bn >> 3) + wc * 8 + j * 2 +
                      (lrow >> 3)];
    }
  };
  auto UPDATE_SZ = [&]() {
#pragma unroll
    for (int j = 0; j < 4; ++j) {
      scC[j] = scN[j];
      const float zp = (float)(((zwN[j] >> shz) & 15) + 1);
      zscC[j] = -zp * scC[j];
    }
  };

  f32x4 acc[8][4] = {};

  auto BODY = [&](int q, bool doStage) {
    const int slot = q & 3;
    const char* sa = &lds[slot * 16384];
    const char* sq = &lds[slot * 4096];
    int w[4];
#pragma unroll
    for (int j = 0; j < 4; ++j) w[j] = *(const int*)(sq + offBq[j]);
    short8 af[4];
#pragma unroll
    for (int i = 0; i < 4; ++i) af[i] = *(const short8*)(sa + baseA + i * 1024);
    if (doStage) STAGE((q + 3) & 3, q + 3);
    short8 bf[4];
#pragma unroll
    for (int j = 0; j < 4; ++j) bf[j] = dq8(w[j], scC[j], zscC[j]);
    __builtin_amdgcn_s_setprio(1);
#pragma unroll
    for (int i = 0; i < 4; ++i)
#pragma unroll
      for (int j = 0; j < 4; ++j)
        acc[i][j] = __builtin_amdgcn_mfma_f32_16x16x32_bf16(
            af[i], bf[j], acc[i][j], 0, 0, 0);
    __builtin_amdgcn_s_setprio(0);
    short8 af2[4];
#pragma unroll
    for (int i = 0; i < 4; ++i)
      af2[i] = *(const short8*)(sa + baseA + 4096 + i * 1024);
    __builtin_amdgcn_s_setprio(1);
#pragma unroll
    for (int i = 0; i < 4; ++i)
#pragma unroll
      for (int j = 0; j < 4; ++j)
        acc[4 + i][j] = __builtin_amdgcn_mfma_f32_16x16x32_bf16(
            af2[i], bf[j], acc[4 + i][j], 0, 0, 0);
    __builtin_amdgcn_s_setprio(0);
  };

  // --- prologue: SZ(group0) [8 loads] + stage slots 0,1,2 [12 loads];
  //     vmcnt(4) -> SZ + slots 0,1 landed (slot 2 in flight)
  LOADSZ(0);
  STAGE(0, 0);
  STAGE(1, 1);
  STAGE(2, 2);
  wait_vm4();
  bar();

  // --- main: groups 0..G-2 (4 bodies each, all staging) ---
  for (int g = 0; g < G - 1; ++g) {
    const int q0 = 4 * g;
    UPDATE_SZ();
    BODY(q0, true);            // entry sync for q0 done above / at loop tail
    wait_vm8(); bar();
    BODY(q0 + 1, true);
    wait_vm8(); bar();
    BODY(q0 + 2, true);
    wait_vm8(); bar();
    LOADSZ(g + 1);             // 8 SZ loads BEFORE qq3's stage (ledger)
    BODY(q0 + 3, true);
    wait_vm4(); bar();         // entry sync for next group's qq0
  }
  // --- last group (peeled): P-4 stages slot P-1; then drain ---
  {
    const int q0 = P - 4;
    UPDATE_SZ();
    BODY(q0, true);
    wait_vm8(); bar();
    BODY(q0 + 1, false);
    wait_vm4(); bar();
    BODY(q0 + 2, false);
    wait_vm0(); bar();
    BODY(q0 + 3, false);
  }

  // --- epilogue: C = acc + bias. C/D map: col=lane&15, row=(lane>>4)*4+reg
  const int crow0 = bm + wr * 128 + (lane >> 4) * 4;
  const int ccol0 = bn + wc * 64 + (lane & 15);
#pragma unroll
  for (int j = 0; j < 4; ++j) {
    const float bv = bias[ccol0 + j * 16];
#pragma unroll
    for (int i = 0; i < 8; ++i) {
#pragma unroll
      for (int r = 0; r < 4; ++r) {
        C[(size_t)(crow0 + i * 16 + r) * N + ccol0 + j * 16] =
            acc[i][j][r] + bv;
      }
    }
  }
}

// ---------------------------------------------------------------------------
// 128x128x64 GEMM (fallback for non-256-divisible shapes).
// ---------------------------------------------------------------------------
#define BM 128
#define BN 128
#define BK 64

template <bool A_BF16>
__global__ __launch_bounds__(256) void gemm_bias_kernel(
    const void* __restrict__ Av, const short* __restrict__ Bt,
    const float* __restrict__ bias, float* __restrict__ C,
    int M, int N, int K) {
  __shared__ __align__(16) short As[BM * BK];
  __shared__ __align__(16) short Bs[BN * BK];
  const int tid = threadIdx.x;
  const int bm = blockIdx.y * BM;
  const int bn = blockIdx.x * BN;
  const int wid = tid >> 6, lane = tid & 63;
  const int wr = wid >> 1, wc = wid & 1;
  const int lrow = lane & 15;
  const int lk = (lane >> 4) * 8;

  f32x4 acc[4][4] = {};

  for (int kt = 0; kt < K; kt += BK) {
    if constexpr (A_BF16) {
      const short* A = (const short*)Av;
#pragma unroll
      for (int r = 0; r < 4; ++r) {
        const int c = r * 256 + tid;
        const int row = c >> 3, ch = c & 7;
        gload_lds16(A + (size_t)(bm + row) * K + kt + ch * 8,
                    (char*)As + c * 16);
      }
    } else {
      const float* A = (const float*)Av;
#pragma unroll
      for (int r = 0; r < 4; ++r) {
        const int c = r * 256 + tid;
        const int row = c >> 3, ch = c & 7;
        const float* src = A + (size_t)(bm + row) * K + kt + ch * 8;
        float4 f0 = *(const float4*)src;
        float4 f1 = *(const float4*)(src + 4);
        short8 v;
        v[0] = f2bf(f0.x); v[1] = f2bf(f0.y); v[2] = f2bf(f0.z); v[3] = f2bf(f0.w);
        v[4] = f2bf(f1.x); v[5] = f2bf(f1.y); v[6] = f2bf(f1.z); v[7] = f2bf(f1.w);
        *(short8*)((char*)As + c * 16) = v;
      }
    }
#pragma unroll
    for (int r = 0; r < 4; ++r) {
      const int c = r * 256 + tid;
      const int row = c >> 3, ch = c & 7;
      gload_lds16(Bt + (size_t)(bn + row) * K + kt + ch * 8,
                  (char*)Bs + c * 16);
    }
    __syncthreads();
#pragma unroll
    for (int kk = 0; kk < 2; ++kk) {
      short8 af[4], bf[4];
#pragma unroll
      for (int i = 0; i < 4; ++i)
        af[i] = *(const short8*)&As[(wr * 64 + i * 16 + lrow) * BK + kk * 32 + lk];
#pragma unroll
      for (int j = 0; j < 4; ++j)
        bf[j] = *(const short8*)&Bs[(wc * 64 + j * 16 + lrow) * BK + kk * 32 + lk];
#pragma unroll
      for (int i = 0; i < 4; ++i)
#pragma unroll
        for (int j = 0; j < 4; ++j)
          acc[i][j] = __builtin_amdgcn_mfma_f32_16x16x32_bf16(
              af[i], bf[j], acc[i][j], 0, 0, 0);
    }
    __syncthreads();
  }

  const int crow0 = bm + wr * 64 + (lane >> 4) * 4;
  const int ccol0 = bn + wc * 64 + (lane & 15);
#pragma unroll
  for (int j = 0; j < 4; ++j) {
    const float bv = bias[ccol0 + j * 16];
#pragma unroll
    for (int i = 0; i < 4; ++i) {
#pragma unroll
      for (int r = 0; r < 4; ++r) {
        C[(size_t)(crow0 + i * 16 + r) * N + ccol0 + j * 16] = acc[i][j][r] + bv;
      }
    }
  }
}

// ---------------------------------------------------------------------------
// Last-resort fallback: naive fused dequant GEMM.
// ---------------------------------------------------------------------------
__global__ __launch_bounds__(256) void naive_kernel(
    const float* __restrict__ x, const float* __restrict__ scales,
    const float* __restrict__ bias, const int* __restrict__ qw,
    const int* __restrict__ qz, float* __restrict__ out,
    int M, int K, int N) {
  long idx = (long)blockIdx.x * blockDim.x + threadIdx.x;
  if (idx >= (long)M * N) return;
  const int n = (int)(idx % N);
  const int m = (int)(idx / N);
  float acc = 0.f;
  for (int g = 0; g < K / 128; ++g) {
    const float sc = scales[(size_t)g * N + n];
    const float zp =
        (float)(((qz[(size_t)g * (N >> 3) + (n >> 3)] >> ((n & 7) * 4)) & 15) + 1);
    const float zs = zp * sc;
    for (int kw = 0; kw < 16; ++kw) {
      const int w = qw[(size_t)(g * 16 + kw) * N + n];
      const float* xp = &x[(size_t)m * K + g * 128 + kw * 8];
#pragma unroll
      for (int e = 0; e < 8; ++e)
        acc += xp[e] * ((float)((w >> (4 * e)) & 15) * sc - zs);
    }
  }
  out[idx] = acc + bias[n];
}

// ---------------------------------------------------------------------------
extern "C" void kernel_launch(void* const* d_in, const int* in_sizes, int n_in,
                              void* d_out, int out_size, void* d_ws,
                              size_t ws_size, hipStream_t stream) {
  const float* x = (const float*)d_in[0];
  const float* scales = (const float*)d_in[1];
  const float* bias = (const float*)d_in[2];
  const int* qweight = (const int*)d_in[3];
  const int* qzeros = (const int*)d_in[4];
  float* out = (float*)d_out;

  const int out_f = in_sizes[2];            // 12288
  const int kwords = in_sizes[3] / out_f;   // 512
  const int in_f = kwords * 8;              // 4096
  const int tokens = in_sizes[0] / in_f;    // 8192
  const int M = tokens, K = in_f, N = out_f;

  const size_t wt_bytes = (size_t)K * N * sizeof(short);
  const size_t xb_bytes = (size_t)M * K * sizeof(short);

  const bool div128 = (M % BM == 0) && (N % BN == 0) && (K % BK == 0) &&
                      (K % 128 == 0) && (N % 64 == 0);
  const bool div256 = (M % GBM == 0) && (N % GBN == 0) && (K % 128 == 0);

  if (div256 && ws_size >= xb_bytes) {
    // R6 fused path: only xb workspace needed
    short* xb = (short*)d_ws;
    const long n8 = (long)M * K / 8;
    cvt_kernel<<<(int)((n8 + 255) / 256), 256, 0, stream>>>(x, xb, n8);
    gemm_fused_kernel<<<(M / GBM) * (N / GBN), 512, 0, stream>>>(
        xb, qweight, qzeros, scales, bias, out, M, N, K);
  } else if (div128 && ws_size >= wt_bytes + xb_bytes) {
    short* Wt = (short*)d_ws;
    short* xb = (short*)((char*)d_ws + wt_bytes);
    dequant_kernel<<<dim3(N / 64, K / 64), 256, 0, stream>>>(
        qweight, qzeros, scales, Wt, K, N);
    const long n8 = (long)M * K / 8;
    cvt_kernel<<<(int)((n8 + 255) / 256), 256, 0, stream>>>(x, xb, n8);
    gemm_bias_kernel<true><<<dim3(N / BN, M / BM), 256, 0, stream>>>(
        xb, Wt, bias, out, M, N, K);
  } else if (div128 && ws_size >= wt_bytes) {
    short* Wt = (short*)d_ws;
    dequant_kernel<<<dim3(N / 64, K / 64), 256, 0, stream>>>(
        qweight, qzeros, scales, Wt, K, N);
    gemm_bias_kernel<false><<<dim3(N / BN, M / BM), 256, 0, stream>>>(
        x, Wt, bias, out, M, N, K);
  } else {
    const long total = (long)M * N;
    naive_kernel<<<(int)((total + 255) / 256), 256, 0, stream>>>(
        x, scales, bias, qweight, qzeros, out, M, K, N);
  }
}